// Round 3
// baseline (464.661 us; speedup 1.0000x reference)
//
#include <hip/hip_runtime.h>
#include <hip/hip_bf16.h>
#include <math.h>

#define Nn 32
#define Dd 512
#define Pp 4096
#define Kk 64
#define PSEG 4
static constexpr float EPSF = 1e-12f;

typedef short short8 __attribute__((ext_vector_type(8)));
typedef float floatx4 __attribute__((ext_vector_type(4)));

static __device__ __forceinline__ int f2b2(float a, float b) {
  __hip_bfloat162 h = __float22bfloat162_rn(float2{a, b});
  int r; __builtin_memcpy(&r, &h, 4); return r;
}
static __device__ __forceinline__ short8 pack8(const float* v) {
  union { short8 s; int i[4]; } u;
  u.i[0] = f2b2(v[0], v[1]); u.i[1] = f2b2(v[2], v[3]);
  u.i[2] = f2b2(v[4], v[5]); u.i[3] = f2b2(v[6], v[7]);
  return u.s;
}
static __device__ __forceinline__ short f2b1(float f) {
  unsigned u = __float_as_uint(f);
  return (short)((u + 0x7FFFu + ((u >> 16) & 1u)) >> 16);
}
static __device__ __forceinline__ float b2f(short s) {
  return __uint_as_float(((unsigned)(unsigned short)s) << 16);
}

// ---------------------------------------------------------------------------
// K0: prepack w -> bf16 in B-fragment order wp[chunk][k][q][8],
// chunk = d/32, q = kk-quad. 1024 threads total.
// ---------------------------------------------------------------------------
__global__ __launch_bounds__(256) void k_wpack(
    const float* __restrict__ w, short* __restrict__ wp)
{
  int id = blockIdx.x * 256 + threadIdx.x;     // (chunk, k): 16*64 = 1024
  int chunk = id >> 6, k = id & 63;
  const float* src = w + (size_t)k * Dd + chunk * 32;
  short* dst = wp + ((size_t)(chunk * 64 + k)) * 32;
#pragma unroll
  for (int q = 0; q < 4; ++q) {
    float v[8];
    *(float4*)&v[0] = *(const float4*)(src + q * 8);
    *(float4*)&v[4] = *(const float4*)(src + q * 8 + 4);
    *(short8*)(dst + q * 8) = pack8(v);
  }
}

// ---------------------------------------------------------------------------
// K1: fused norm + logits (MFMA, operands flipped: A=x, B=w) + softmax.
// grid: Nn*32 = 1024 blocks x 256 thr. Block = (n, 128 px); wave = 32 px.
// LDS-free main loop: A-frags = 8 coalesced scalar x-loads (64-B segments),
// B-frags = 16-B reads from prepacked wp (L2-hot). ssq piggybacks on A values.
// Writes a_s = softmax(logits*inv) * inv (bf16) and asum (fp32 atomics).
// ---------------------------------------------------------------------------
__global__ __launch_bounds__(256) void k_assign(
    const float* __restrict__ x, const short* __restrict__ wp,
    short* __restrict__ a_s, float* __restrict__ asum)
{
  __shared__ short ab4[4][2048];   // per-wave a staging [k][px_local 32]
  __shared__ float invs[128];

  const int tid = threadIdx.x;
  const int n  = blockIdx.x >> 5;
  const int p0 = (blockIdx.x & 31) * 128;
  const int wave = tid >> 6, lane = tid & 63;
  const int q = lane >> 4, pc = lane & 15;
  const int wpx = wave * 32;

  floatx4 acc[4][2];
#pragma unroll
  for (int t = 0; t < 4; ++t)
#pragma unroll
    for (int s = 0; s < 2; ++s) acc[t][s] = floatx4{0.f, 0.f, 0.f, 0.f};
  float sq[2] = {0.f, 0.f};

  // A-operand: lane reads x[dc + q*8 + j][p0 + wpx + s*16 + pc]
  const float* xa0 = x + (size_t)n * Dd * Pp + (size_t)(q * 8) * Pp + p0 + wpx + pc;
  const float* xa1 = xa0 + 16;

  for (int dc = 0; dc < Dd; dc += 32) {
    short8 bf[4];
    const short* wc = wp + (size_t)(dc >> 5) * 2048 + pc * 32 + q * 8;
#pragma unroll
    for (int t = 0; t < 4; ++t)
      bf[t] = *(const short8*)(wc + t * 512);
    float v0[8], v1[8];
#pragma unroll
    for (int j = 0; j < 8; ++j) {
      float a0 = xa0[(size_t)j * Pp];
      float a1 = xa1[(size_t)j * Pp];
      v0[j] = a0; v1[j] = a1;
      sq[0] += a0 * a0; sq[1] += a1 * a1;
    }
    short8 af0 = pack8(v0), af1 = pack8(v1);
#pragma unroll
    for (int t = 0; t < 4; ++t) {
      acc[t][0] = __builtin_amdgcn_mfma_f32_16x16x32_bf16(af0, bf[t], acc[t][0], 0, 0, 0);
      acc[t][1] = __builtin_amdgcn_mfma_f32_16x16x32_bf16(af1, bf[t], acc[t][1], 0, 0, 0);
    }
    xa0 += (size_t)32 * Pp; xa1 += (size_t)32 * Pp;
  }

  // per-pixel inv norm: reduce ssq over q-quarters (lanes 16 apart)
#pragma unroll
  for (int s = 0; s < 2; ++s) {
    float t = sq[s];
    t += __shfl_xor(t, 16);
    t += __shfl_xor(t, 32);
    if (q == 0) invs[wpx + s * 16 + pc] = 1.f / fmaxf(sqrtf(t), EPSF);
  }
  // intra-wave LDS write->read; compiler inserts lgkmcnt
  float ivr[2][4];
#pragma unroll
  for (int s = 0; s < 2; ++s)
#pragma unroll
    for (int r = 0; r < 4; ++r)
      ivr[s][r] = invs[wpx + s * 16 + q * 4 + r];

  // softmax over k per C-row (row = px = q*4+r, col = k = t*16+pc):
  // reduce across lanes 1,2,4,8 (the pc group)
#pragma unroll
  for (int s = 0; s < 2; ++s)
#pragma unroll
    for (int r = 0; r < 4; ++r) {
      float l[4];
#pragma unroll
      for (int t = 0; t < 4; ++t) l[t] = acc[t][s][r] * ivr[s][r];
      float mx = fmaxf(fmaxf(l[0], l[1]), fmaxf(l[2], l[3]));
      mx = fmaxf(mx, __shfl_xor(mx, 1));
      mx = fmaxf(mx, __shfl_xor(mx, 2));
      mx = fmaxf(mx, __shfl_xor(mx, 4));
      mx = fmaxf(mx, __shfl_xor(mx, 8));
      float e[4], sm = 0.f;
#pragma unroll
      for (int t = 0; t < 4; ++t) { e[t] = __expf(l[t] - mx); sm += e[t]; }
      sm += __shfl_xor(sm, 1);
      sm += __shfl_xor(sm, 2);
      sm += __shfl_xor(sm, 4);
      sm += __shfl_xor(sm, 8);
      float si = 1.f / sm;
      int pl = s * 16 + q * 4 + r;
#pragma unroll
      for (int t = 0; t < 4; ++t)
        ab4[wave][(t * 16 + pc) * 32 + pl] = f2b1(e[t] * si);
    }

  // readout rows: asum partial + a_s = a*inv store (b128), all intra-wave
#pragma unroll
  for (int pass = 0; pass < 4; ++pass) {
    int kr = pass * 16 + (lane >> 2);
    int c8 = (lane & 3) * 8;
    short8 av = *(short8*)&ab4[wave][kr * 32 + c8];
    float aw[8]; float s8 = 0.f;
#pragma unroll
    for (int i = 0; i < 8; ++i) { aw[i] = b2f(av[i]); s8 += aw[i]; }
    s8 += __shfl_down(s8, 1);
    s8 += __shfl_down(s8, 2);
    if ((lane & 3) == 0) atomicAdd(&asum[n * Kk + kr], s8);
    float ivv[8];
    *(float4*)&ivv[0] = *(const float4*)&invs[wpx + c8];
    *(float4*)&ivv[4] = *(const float4*)&invs[wpx + c8 + 4];
    float ov[8];
#pragma unroll
    for (int i = 0; i < 8; ++i) ov[i] = aw[i] * ivv[i];
    *(short8*)(a_s + ((size_t)(n * Kk + kr)) * Pp + p0 + wpx + c8) = pack8(ov);
  }
}

// ---------------------------------------------------------------------------
// K2: vlad partials via MFMA, LDS-free. vpart[ps][n][k][d] = sum_{p in seg}
// a_s[n,k,p] * x[n,d,p]. grid: n(32) x dt(4) x ps(4) = 512 blocks x 256 thr.
// ---------------------------------------------------------------------------
__global__ __launch_bounds__(256) void k_vlad(
    const float* __restrict__ x, const short* __restrict__ a_s,
    float* __restrict__ vpart)
{
  const int tid = threadIdx.x;
  const int ps = blockIdx.x & 3;
  const int dt = (blockIdx.x >> 2) & 3;
  const int n  = blockIdx.x >> 4;
  const int wave = tid >> 6, lane = tid & 63;
  const int q = lane >> 4, pc = lane & 15;
  const int dw = dt * 128 + wave * 32;
  const int pb = ps * (Pp / PSEG);

  floatx4 acc[4][2];
#pragma unroll
  for (int t = 0; t < 4; ++t)
#pragma unroll
    for (int s = 0; s < 2; ++s) acc[t][s] = floatx4{0.f, 0.f, 0.f, 0.f};

  const short* ab0 = a_s + ((size_t)(n * Kk + pc)) * Pp + q * 8;
  const float* xb0 = x + ((size_t)(n * Dd + dw + pc)) * Pp + q * 8;

#pragma unroll 2
  for (int p = pb; p < pb + Pp / PSEG; p += 32) {
    short8 af[4];
#pragma unroll
    for (int t = 0; t < 4; ++t)
      af[t] = *(const short8*)(ab0 + (size_t)t * 16 * Pp + p);
    short8 bf[2];
#pragma unroll
    for (int s = 0; s < 2; ++s) {
      const float* xp = xb0 + (size_t)s * 16 * Pp + p;
      float bv[8];
      *(float4*)&bv[0] = *(const float4*)xp;
      *(float4*)&bv[4] = *(const float4*)(xp + 4);
      bf[s] = pack8(bv);
    }
#pragma unroll
    for (int t = 0; t < 4; ++t)
#pragma unroll
      for (int s = 0; s < 2; ++s)
        acc[t][s] = __builtin_amdgcn_mfma_f32_16x16x32_bf16(af[t], bf[s], acc[t][s], 0, 0, 0);
  }

  float* vb = vpart + (((size_t)ps * Nn + n) * Kk) * Dd;
#pragma unroll
  for (int t = 0; t < 4; ++t)
#pragma unroll
    for (int s = 0; s < 2; ++s)
#pragma unroll
      for (int r = 0; r < 4; ++r)
        vb[(size_t)(t * 16 + q * 4 + r) * Dd + dw + s * 16 + pc] = acc[t][s][r];
}

// ---------------------------------------------------------------------------
// K3: combine partials, subtract asum*centroid, intra-normalize over D,
// accumulate global sumsq per n. grid: Nn*Kk = 2048 blocks, 128 threads
// ---------------------------------------------------------------------------
__global__ __launch_bounds__(128) void k_intra(
    const float* __restrict__ vpart, const float* __restrict__ asum,
    const float* __restrict__ cent, float* __restrict__ out, float* __restrict__ gnsq)
{
  __shared__ float red[2];
  const int nk = blockIdx.x;
  const int n = nk >> 6, k = nk & 63;
  const int tid = threadIdx.x;
  const int d = tid * 4;

  float4 v = {0.f, 0.f, 0.f, 0.f};
#pragma unroll
  for (int ps = 0; ps < PSEG; ++ps) {
    float4 t = *(const float4*)&vpart[(((size_t)ps * Nn + n) * Kk + k) * Dd + d];
    v.x += t.x; v.y += t.y; v.z += t.z; v.w += t.w;
  }
  float s = asum[n * Kk + k];
  float4 c = *(const float4*)&cent[(size_t)k * Dd + d];
  v.x -= s * c.x; v.y -= s * c.y; v.z -= s * c.z; v.w -= s * c.w;

  float qq = v.x * v.x + v.y * v.y + v.z * v.z + v.w * v.w;
#pragma unroll
  for (int off = 32; off; off >>= 1) qq += __shfl_down(qq, off);
  if ((tid & 63) == 0) red[tid >> 6] = qq;
  __syncthreads();
  float norm = sqrtf(red[0] + red[1]);
  float r = 1.f / fmaxf(norm, EPSF);
  v.x *= r; v.y *= r; v.z *= r; v.w *= r;
  *(float4*)&out[(size_t)n * (Kk * Dd) + (size_t)k * Dd + d] = v;
  if (tid == 0) {
    float t = norm * r;   // 1 unless degenerate row
    atomicAdd(&gnsq[n], t * t);
  }
}

// ---------------------------------------------------------------------------
// K4: global L2 scale per n (in-place on out)
// ---------------------------------------------------------------------------
__global__ __launch_bounds__(256) void k_gscale(
    float* __restrict__ out, const float* __restrict__ gnsq)
{
  size_t i = ((size_t)blockIdx.x * 256 + threadIdx.x) * 4;
  int n = (int)(i >> 15);   // K*D = 32768 per n
  float r = 1.f / fmaxf(sqrtf(gnsq[n]), EPSF);
  float4 v = *(float4*)&out[i];
  v.x *= r; v.y *= r; v.z *= r; v.w *= r;
  *(float4*)&out[i] = v;
}

extern "C" void kernel_launch(void* const* d_in, const int* in_sizes, int n_in,
                              void* d_out, int out_size, void* d_ws, size_t ws_size,
                              hipStream_t stream) {
  (void)in_sizes; (void)n_in; (void)out_size; (void)ws_size;
  const float* x    = (const float*)d_in[0];   // [N,D,H,W]
  const float* w    = (const float*)d_in[1];   // [K,D]
  const float* cent = (const float*)d_in[2];   // [K,D]
  float* out = (float*)d_out;

  // ws: a_s bf16 [N*K*P] | asum f32 [2048] | gnsq f32 [64] |
  //     vpart f32 [PSEG*N*K*D] | wp bf16 [16*64*32]
  short* a_s   = (short*)d_ws;
  float* asum  = (float*)(a_s + (size_t)Nn * Kk * Pp);
  float* gnsq  = asum + Nn * Kk;
  float* vpart = gnsq + 64;
  short* wpk   = (short*)(vpart + (size_t)PSEG * Nn * Kk * Dd);

  hipMemsetAsync(asum, 0, (Nn * Kk + 64) * sizeof(float), stream);
  k_wpack<<<4, 256, 0, stream>>>(w, wpk);
  k_assign<<<Nn * 32, 256, 0, stream>>>(x, wpk, a_s, asum);
  k_vlad<<<Nn * 4 * PSEG, 256, 0, stream>>>(x, a_s, vpart);
  k_intra<<<Nn * Kk, 128, 0, stream>>>(vpart, asum, cent, out, gnsq);
  k_gscale<<<(Nn * Kk * Dd) / (256 * 4), 256, 0, stream>>>(out, gnsq);
}

// Round 4
// 418.995 us; speedup vs baseline: 1.1090x; 1.1090x over previous
//
#include <hip/hip_runtime.h>
#include <hip/hip_bf16.h>
#include <math.h>

#define Nn 32
#define Dd 512
#define Pp 4096
#define Kk 64
#define SEG 16           // p-segments (blocks per n)
#define PXB 256          // px per block
#define PT 64            // px per p-tile
static constexpr float EPSF = 1e-12f;

typedef short short8 __attribute__((ext_vector_type(8)));
typedef short short4v __attribute__((ext_vector_type(4)));
typedef float floatx4 __attribute__((ext_vector_type(4)));

static __device__ __forceinline__ int f2b2(float a, float b) {
  __hip_bfloat162 h = __float22bfloat162_rn(float2{a, b});
  int r; __builtin_memcpy(&r, &h, 4); return r;
}
static __device__ __forceinline__ short8 pack8(const float* v) {
  union { short8 s; int i[4]; } u;
  u.i[0] = f2b2(v[0], v[1]); u.i[1] = f2b2(v[2], v[3]);
  u.i[2] = f2b2(v[4], v[5]); u.i[3] = f2b2(v[6], v[7]);
  return u.s;
}
static __device__ __forceinline__ short f2b1(float f) {
  unsigned u = __float_as_uint(f);
  return (short)((u + 0x7FFFu + ((u >> 16) & 1u)) >> 16);
}
static __device__ __forceinline__ float b2f(short s) {
  return __uint_as_float(((unsigned)(unsigned short)s) << 16);
}

// ---------------------------------------------------------------------------
// K0: prepack w -> bf16 B-fragment order wp[chunk][k][q][8]  (L2-hot, 64 KB)
// ---------------------------------------------------------------------------
__global__ __launch_bounds__(256) void k_wpack(
    const float* __restrict__ w, short* __restrict__ wp)
{
  int id = blockIdx.x * 256 + threadIdx.x;     // (chunk, k): 16*64 = 1024
  int chunk = id >> 6, k = id & 63;
  const float* src = w + (size_t)k * Dd + chunk * 32;
  short* dst = wp + ((size_t)(chunk * 64 + k)) * 32;
#pragma unroll
  for (int q = 0; q < 4; ++q) {
    float v[8];
    *(float4*)&v[0] = *(const float4*)(src + q * 8);
    *(float4*)&v[4] = *(const float4*)(src + q * 8 + 4);
    *(short8*)(dst + q * 8) = pack8(v);
  }
}

// ---------------------------------------------------------------------------
// K1: FUSED norm + logits + softmax + vlad-partial.
// grid: 32 n x 16 segs = 512 blocks x 256 thr; 2 blocks/CU.
// Per 64-px tile: GEMM1 (A = x from global scalar loads, B = wp) with x
// simultaneously re-read as float4 (L1-hot) and stashed bf16 in LDS xb.
// Softmax in-register per wave; a*inv -> LDS a_s. GEMM2 from LDS only,
// acc [64k x 128d] per wave held in VGPRs across all 4 tiles.
// Outputs: vpart bf16 [seg][n][k][d], asum fp32 atomics.
// ---------------------------------------------------------------------------
__global__ __launch_bounds__(256, 2) void k_fused(
    const float* __restrict__ x, const short* __restrict__ wp,
    float* __restrict__ asum, short* __restrict__ vpart)
{
  constexpr int XS = 64;   // xb row stride (shorts); unpadded (LDS not bottleneck)
  constexpr int AS = 72;   // a_s row stride (16B-aligned rows)
  __shared__ short xb[Dd * XS];      // 64 KB  x tile bf16 [d][px]
  __shared__ short as_[Kk * AS];     // 9 KB   a*inv bf16  [k][px]
  __shared__ float invs[PT];

  const int tid = threadIdx.x;
  const int n = blockIdx.x >> 4, seg = blockIdx.x & 15;
  const int wave = tid >> 6, lane = tid & 63;
  const int q = lane >> 4, pc = lane & 15;
  const int sd = tid >> 3, sc = tid & 7;     // stage loader coords

  floatx4 acc2[4][8];                        // [k-tile][d-tile] = 128 VGPRs
#pragma unroll
  for (int t = 0; t < 4; ++t)
#pragma unroll
    for (int s2 = 0; s2 < 8; ++s2) acc2[t][s2] = floatx4{0.f, 0.f, 0.f, 0.f};
  float asr[4] = {0.f, 0.f, 0.f, 0.f};       // asum partials (k = t*16+pc)

  const float* xn = x + (size_t)n * Dd * Pp;

  for (int pt = 0; pt < PXB / PT; ++pt) {
    const int p0 = seg * PXB + pt * PT;
    __syncthreads();                         // xb/a_s free to overwrite

    floatx4 acc1[4];
#pragma unroll
    for (int t = 0; t < 4; ++t) acc1[t] = floatx4{0.f, 0.f, 0.f, 0.f};
    float sq = 0.f;

    const float* xa = xn + (size_t)(q * 8) * Pp + p0 + wave * 16 + pc;
    const float* xs = xn + (size_t)sd * Pp + p0 + sc * 8;

    for (int dc = 0; dc < Dd; dc += 32) {
      // stage: re-read (L1-hot) as float4, stash bf16 tile [d][px]
      float4 u0 = *(const float4*)xs;
      float4 u1 = *(const float4*)(xs + 4);
      int2 w0 = { f2b2(u0.x, u0.y), f2b2(u0.z, u0.w) };
      int2 w1 = { f2b2(u1.x, u1.y), f2b2(u1.z, u1.w) };
      *(int2*)&xb[(dc + sd) * XS + sc * 8] = w0;
      *(int2*)&xb[(dc + sd) * XS + sc * 8 + 4] = w1;
      xs += (size_t)32 * Pp;
      // A-frag: 8 scalar x loads (coalesced 64B segments), ssq piggyback
      float v[8];
#pragma unroll
      for (int j = 0; j < 8; ++j) {
        float a = xa[(size_t)j * Pp];
        v[j] = a; sq += a * a;
      }
      xa += (size_t)32 * Pp;
      short8 af = pack8(v);
      // B-frags from prepacked w (L2-hot) + MFMA
      const short* wc = wp + (size_t)(dc >> 5) * 2048 + pc * 32 + q * 8;
#pragma unroll
      for (int t = 0; t < 4; ++t) {
        short8 bf = *(const short8*)(wc + t * 512);
        acc1[t] = __builtin_amdgcn_mfma_f32_16x16x32_bf16(af, bf, acc1[t], 0, 0, 0);
      }
    }

    // per-pixel inv-norm (lane pc owns px = wave*16+pc partial over its q-quarter)
    {
      float tsum = sq;
      tsum += __shfl_xor(tsum, 16);
      tsum += __shfl_xor(tsum, 32);
      if (q == 0) invs[wave * 16 + pc] = 1.f / fmaxf(sqrtf(tsum), EPSF);
    }
    float ivr[4];
#pragma unroll
    for (int r = 0; r < 4; ++r) ivr[r] = invs[wave * 16 + q * 4 + r];

    // softmax over k per C-row (row = px = q*4+r, col = k = t*16+pc)
#pragma unroll
    for (int r = 0; r < 4; ++r) {
      float l[4];
#pragma unroll
      for (int t = 0; t < 4; ++t) l[t] = acc1[t][r] * ivr[r];
      float mx = fmaxf(fmaxf(l[0], l[1]), fmaxf(l[2], l[3]));
      mx = fmaxf(mx, __shfl_xor(mx, 1));
      mx = fmaxf(mx, __shfl_xor(mx, 2));
      mx = fmaxf(mx, __shfl_xor(mx, 4));
      mx = fmaxf(mx, __shfl_xor(mx, 8));
      float e[4], sm = 0.f;
#pragma unroll
      for (int t = 0; t < 4; ++t) { e[t] = __expf(l[t] - mx); sm += e[t]; }
      sm += __shfl_xor(sm, 1);
      sm += __shfl_xor(sm, 2);
      sm += __shfl_xor(sm, 4);
      sm += __shfl_xor(sm, 8);
      float si = 1.f / sm;
#pragma unroll
      for (int t = 0; t < 4; ++t) {
        float av = e[t] * si;                 // plain a
        asr[t] += av;
        as_[(t * 16 + pc) * AS + wave * 16 + q * 4 + r] = f2b1(av * ivr[r]);
      }
    }
    __syncthreads();                          // xb + a_s complete

    // GEMM2: vlad acc += a_s[k][p] * xb[d][p], all from LDS (b128 frags)
#pragma unroll
    for (int c = 0; c < 2; ++c) {             // kk-chunks of 32 px
      short8 af2[4];
#pragma unroll
      for (int t = 0; t < 4; ++t)
        af2[t] = *(const short8*)&as_[(t * 16 + pc) * AS + c * 32 + q * 8];
#pragma unroll
      for (int s2 = 0; s2 < 8; ++s2) {
        short8 bf2 = *(const short8*)&xb[(wave * 128 + s2 * 16 + pc) * XS + c * 32 + q * 8];
#pragma unroll
        for (int t = 0; t < 4; ++t)
          acc2[t][s2] = __builtin_amdgcn_mfma_f32_16x16x32_bf16(af2[t], bf2, acc2[t][s2], 0, 0, 0);
      }
    }
  }

  // epilogue: asum atomics + vpart bf16 stores
#pragma unroll
  for (int t = 0; t < 4; ++t) {
    float v = asr[t];
    v += __shfl_xor(v, 16);
    v += __shfl_xor(v, 32);
    if (q == 0) atomicAdd(&asum[n * Kk + t * 16 + pc], v);
  }
  short* vb = vpart + ((size_t)(seg * Nn + n) * Kk) * Dd;
#pragma unroll
  for (int t = 0; t < 4; ++t)
#pragma unroll
    for (int s2 = 0; s2 < 8; ++s2)
#pragma unroll
      for (int r = 0; r < 4; ++r)
        vb[(size_t)(t * 16 + q * 4 + r) * Dd + wave * 128 + s2 * 16 + pc] =
            f2b1(acc2[t][s2][r]);
}

// ---------------------------------------------------------------------------
// K2: combine 16 bf16 partials, subtract asum*centroid, intra-normalize,
// accumulate global sumsq. grid: Nn*Kk = 2048 blocks x 128 thr.
// ---------------------------------------------------------------------------
__global__ __launch_bounds__(128) void k_intra(
    const short* __restrict__ vpart, const float* __restrict__ asum,
    const float* __restrict__ cent, float* __restrict__ out, float* __restrict__ gnsq)
{
  __shared__ float red[2];
  const int nk = blockIdx.x;
  const int n = nk >> 6, k = nk & 63;
  const int tid = threadIdx.x;
  const int d = tid * 4;

  float4 v = {0.f, 0.f, 0.f, 0.f};
#pragma unroll
  for (int ps = 0; ps < SEG; ++ps) {
    short4v t = *(const short4v*)&vpart[((size_t)(ps * Nn + n) * Kk + k) * Dd + d];
    v.x += b2f(t[0]); v.y += b2f(t[1]); v.z += b2f(t[2]); v.w += b2f(t[3]);
  }
  float s = asum[n * Kk + k];
  float4 c = *(const float4*)&cent[(size_t)k * Dd + d];
  v.x -= s * c.x; v.y -= s * c.y; v.z -= s * c.z; v.w -= s * c.w;

  float qq = v.x * v.x + v.y * v.y + v.z * v.z + v.w * v.w;
#pragma unroll
  for (int off = 32; off; off >>= 1) qq += __shfl_down(qq, off);
  if ((tid & 63) == 0) red[tid >> 6] = qq;
  __syncthreads();
  float norm = sqrtf(red[0] + red[1]);
  float r = 1.f / fmaxf(norm, EPSF);
  v.x *= r; v.y *= r; v.z *= r; v.w *= r;
  *(float4*)&out[(size_t)n * (Kk * Dd) + (size_t)k * Dd + d] = v;
  if (tid == 0) {
    float t = norm * r;   // 1 unless degenerate row
    atomicAdd(&gnsq[n], t * t);
  }
}

// ---------------------------------------------------------------------------
// K3: global L2 scale per n (in-place on out)
// ---------------------------------------------------------------------------
__global__ __launch_bounds__(256) void k_gscale(
    float* __restrict__ out, const float* __restrict__ gnsq)
{
  size_t i = ((size_t)blockIdx.x * 256 + threadIdx.x) * 4;
  int n = (int)(i >> 15);   // K*D = 32768 per n
  float r = 1.f / fmaxf(sqrtf(gnsq[n]), EPSF);
  float4 v = *(float4*)&out[i];
  v.x *= r; v.y *= r; v.z *= r; v.w *= r;
  *(float4*)&out[i] = v;
}

extern "C" void kernel_launch(void* const* d_in, const int* in_sizes, int n_in,
                              void* d_out, int out_size, void* d_ws, size_t ws_size,
                              hipStream_t stream) {
  (void)in_sizes; (void)n_in; (void)out_size; (void)ws_size;
  const float* x    = (const float*)d_in[0];   // [N,D,H,W]
  const float* w    = (const float*)d_in[1];   // [K,D]
  const float* cent = (const float*)d_in[2];   // [K,D]
  float* out = (float*)d_out;

  // ws: asum f32[2048] | gnsq f32[64] | vpart bf16 [SEG*N*K*D] (33.5 MB) | wp bf16
  float* asum  = (float*)d_ws;
  float* gnsq  = asum + Nn * Kk;
  short* vpart = (short*)(gnsq + 64);
  short* wpk   = vpart + (size_t)SEG * Nn * Kk * Dd;

  hipMemsetAsync(asum, 0, (Nn * Kk + 64) * sizeof(float), stream);
  k_wpack<<<4, 256, 0, stream>>>(w, wpk);
  k_fused<<<Nn * SEG, 256, 0, stream>>>(x, wpk, asum, vpart);
  k_intra<<<Nn * Kk, 128, 0, stream>>>(vpart, asum, cent, out, gnsq);
  k_gscale<<<(Nn * Kk * Dd) / (256 * 4), 256, 0, stream>>>(out, gnsq);
}